// Round 5
// baseline (1030.618 us; speedup 1.0000x reference)
//
#include <hip/hip_runtime.h>
#include <math.h>

#define NBLK 784
#define O_ 32
#define N_ 144
#define D_ 16
#define PS 20    // padded LDS row stride for P (floats); 80B rows, float4-aligned
#define RS 148   // padded LDS row stride for R (floats)

// ---- register-only helpers (explicit float4 scalars => guaranteed SROA) ----

// v = P_row(i) * K  (one row of the 4x4 matmul)
#define MROW(pi, vout)                                                        \
    vout.x = fmaf(pi.x, q0_.x, fmaf(pi.y, q1_.x, fmaf(pi.z, q2_.x, pi.w * q3_.x))); \
    vout.y = fmaf(pi.x, q0_.y, fmaf(pi.y, q1_.y, fmaf(pi.z, q2_.y, pi.w * q3_.y))); \
    vout.z = fmaf(pi.x, q0_.z, fmaf(pi.y, q1_.z, fmaf(pi.z, q2_.z, pi.w * q3_.z))); \
    vout.w = fmaf(pi.x, q0_.w, fmaf(pi.y, q1_.w, fmaf(pi.z, q2_.w, pi.w * q3_.w)));

#define ACC4(v, rr, S1v, S2v)                                                 \
    S1v.x = fmaf(rr, v.x, S1v.x);  S1v.y = fmaf(rr, v.y, S1v.y);              \
    S1v.z = fmaf(rr, v.z, S1v.z);  S1v.w = fmaf(rr, v.w, S1v.w);              \
    S2v.x = fmaf(rr * v.x, v.x, S2v.x);  S2v.y = fmaf(rr * v.y, v.y, S2v.y);  \
    S2v.z = fmaf(rr * v.z, v.z, S2v.z);  S2v.w = fmaf(rr * v.w, v.w, S2v.w);

#define QROW(v, mi, igi)                                                      \
    { float dx_ = v.x - mi.x, dy_ = v.y - mi.y, dz_ = v.z - mi.z, dw_ = v.w - mi.w; \
      Q_ = fmaf(dx_ * dx_, igi.x, Q_); Q_ = fmaf(dy_ * dy_, igi.y, Q_);       \
      Q_ = fmaf(dz_ * dz_, igi.z, Q_); Q_ = fmaf(dw_ * dw_, igi.w, Q_); }

#define SH4(v)                                                                \
    v.x += __shfl_xor(v.x, mm, 64); v.y += __shfl_xor(v.y, mm, 64);           \
    v.z += __shfl_xor(v.z, mm, 64); v.w += __shfl_xor(v.w, mm, 64);

// one k-iteration of pass 1 (votes + weighted moments)
#define PASS1(R_EXPR)                                                         \
    s1_0 = f4z; s1_1 = f4z; s1_2 = f4z; s1_3 = f4z;                           \
    s2_0 = f4z; s2_1 = f4z; s2_2 = f4z; s2_3 = f4z;                           \
    rs = 0.f;                                                                 \
    _Pragma("unroll")                                                         \
    for (int k = 0; k < 18; ++k) {                                            \
        const int n = s + (k << 3);                                           \
        const float r_ = (R_EXPR);                                            \
        const float4* Pp_ = (const float4*)(Pbase + k * (8 * PS));            \
        const float4* Kp_ = (const float4*)(Kb2 + k * (8 * D_));              \
        const float4 p0_ = Pp_[0], p1_ = Pp_[1], p2_ = Pp_[2], p3_ = Pp_[3];  \
        const float4 q0_ = Kp_[0], q1_ = Kp_[1], q2_ = Kp_[2], q3_ = Kp_[3];  \
        float4 v_;                                                            \
        rs += r_;                                                             \
        MROW(p0_, v_); ACC4(v_, r_, s1_0, s2_0);                              \
        MROW(p1_, v_); ACC4(v_, r_, s1_1, s2_1);                              \
        MROW(p2_, v_); ACC4(v_, r_, s1_2, s2_2);                              \
        MROW(p3_, v_); ACC4(v_, r_, s1_3, s2_3);                              \
    }                                                                         \
    _Pragma("unroll")                                                         \
    for (int mm = 1; mm < 8; mm <<= 1) {                                      \
        rs += __shfl_xor(rs, mm, 64);                                         \
        SH4(s1_0); SH4(s1_1); SH4(s1_2); SH4(s1_3);                           \
        SH4(s2_0); SH4(s2_1); SH4(s2_2); SH4(s2_3);                           \
    }

#define MU4(mi, s1i) mi.x = s1i.x * ivr_; mi.y = s1i.y * ivr_;                \
                     mi.z = s1i.z * ivr_; mi.w = s1i.w * ivr_;
#define SG4(gi, s2i, mi)                                                      \
    gi.x = fmaf(-mi.x, mi.x, s2i.x * ivr_) + 1e-9f;                           \
    gi.y = fmaf(-mi.y, mi.y, s2i.y * ivr_) + 1e-9f;                           \
    gi.z = fmaf(-mi.z, mi.z, s2i.z * ivr_) + 1e-9f;                           \
    gi.w = fmaf(-mi.w, mi.w, s2i.w * ivr_) + 1e-9f;

// moments -> mu, sig, L, a_out   (inv_temp = IT)
#define STATS(IT)                                                             \
    {                                                                         \
        rs += 1e-9f;                                                          \
        const float ivr_ = 1.0f / rs;                                         \
        MU4(m0, s1_0); MU4(m1, s1_1); MU4(m2, s1_2); MU4(m3, s1_3);           \
        SG4(g0, s2_0, m0); SG4(g1, s2_1, m1); SG4(g2, s2_2, m2); SG4(g3, s2_3, m3); \
        L = __logf(g0.x * g0.y) + __logf(g0.z * g0.w)                         \
          + __logf(g1.x * g1.y) + __logf(g1.z * g1.w)                         \
          + __logf(g2.x * g2.y) + __logf(g2.z * g2.w)                         \
          + __logf(g3.x * g3.y) + __logf(g3.z * g3.w);                        \
        const float cost_ = rs * fmaf(0.5f, L, 16.0f * buv);                  \
        a_out = 1.0f / (1.0f + __expf(-(IT) * (ba - cost_)));                 \
    }

#define RCP4(di, gi) di.x = 1.0f / gi.x; di.y = 1.0f / gi.y;                  \
                     di.z = 1.0f / gi.z; di.w = 1.0f / gi.w;

__global__ __launch_bounds__(256, 3) void convcaps_em(
    const float* __restrict__ poses,
    const float* __restrict__ acts,
    const float* __restrict__ kern,
    const float* __restrict__ beta_a,
    const float* __restrict__ beta_u,
    float* __restrict__ out)
{
    const int pix = blockIdx.x;          // b*196 + ho*14 + wo
    const int b  = pix / 196;
    const int hw = pix - b * 196;
    const int ho = hw / 14;
    const int wo = hw - ho * 14;

    __shared__ __align__(16) float P[N_ * PS];   // pose blocks [n][d]
    __shared__ float A[N_];                      // a_in
    __shared__ float Rm[O_ * RS];                // R*a / logits [o][n]

    const int t = threadIdx.x;

    // ---- load pose block: P[n][d] = poses[b, ho+ki, wo+kj, c, d], n=(ki*3+kj)*16+c
    for (int idx = t; idx < N_ * D_; idx += 256) {
        int n = idx >> 4, d = idx & 15;
        int ki = n / 48, kj = (n >> 4) - ki * 3, c = n & 15;
        P[n * PS + d] = poses[((b * 16 + ho + ki) * 16 + (wo + kj)) * 256 + c * 16 + d];
    }
    if (t < N_) {
        int n = t;
        int ki = n / 48, kj = (n >> 4) - ki * 3, c = n & 15;
        A[n] = acts[((b * 16 + ho + ki) * 16 + (wo + kj)) * 16 + c];
    }
    __syncthreads();

    const int o = t >> 3;                        // 32 capsules
    const int s = t & 7;                         // 8 lanes per capsule, n-slice
    const float buv = beta_u[o];
    const float ba  = beta_a[o];
    const float* Kb2   = kern + (size_t)o * (N_ * D_) + s * D_;
    const float* Pbase = P + s * PS;

    const float4 f4z = make_float4(0.f, 0.f, 0.f, 0.f);
    float4 s1_0, s1_1, s1_2, s1_3, s2_0, s2_1, s2_2, s2_3;
    float4 m0, m1, m2, m3, g0, g1, g2, g3;
    float rs, L, a_out;

    // ===== it 0: R uniform 1/32, so r = A[n]/32 (Rm not yet needed) =====
    PASS1(A[n] * 0.03125f);
    STATS(1.0f);

#pragma unroll 1
    for (int it = 0; it < 2; ++it) {
        // ===== pass 2: logits into Rm =====
        float4 ig0, ig1, ig2, ig3;
        RCP4(ig0, g0); RCP4(ig1, g1); RCP4(ig2, g2); RCP4(ig3, g3);
        const float LC = __logf(a_out + 1e-9f)
                       - 0.5f * (16.0f * 1.8378770664093453f + L);
        __syncthreads();   // pass-1 Rm reads done before overwrite
#pragma unroll
        for (int k = 0; k < 18; ++k) {
            const int n = s + (k << 3);
            const float4* Pp_ = (const float4*)(Pbase + k * (8 * PS));
            const float4* Kp_ = (const float4*)(Kb2 + k * (8 * D_));
            const float4 p0_ = Pp_[0], p1_ = Pp_[1], p2_ = Pp_[2], p3_ = Pp_[3];
            const float4 q0_ = Kp_[0], q1_ = Kp_[1], q2_ = Kp_[2], q3_ = Kp_[3];
            float4 v_;
            float Q_ = 0.f;
            MROW(p0_, v_); QROW(v_, m0, ig0);
            MROW(p1_, v_); QROW(v_, m1, ig1);
            MROW(p2_, v_); QROW(v_, m2, ig2);
            MROW(p3_, v_); QROW(v_, m3, ig3);
            Rm[o * RS + n] = fmaf(-0.5f, Q_, LC);
        }
        __syncthreads();

        // ===== softmax over o (one thread per n); store R*a pre-multiplied =====
        if (t < N_) {
            float v[32];
            float mx = -1e30f;
#pragma unroll
            for (int oo = 0; oo < 32; ++oo) {
                v[oo] = Rm[oo * RS + t];
                mx = fmaxf(mx, v[oo]);
            }
            float sm = 0.f;
#pragma unroll
            for (int oo = 0; oo < 32; ++oo) {
                v[oo] = __expf(v[oo] - mx);
                sm += v[oo];
            }
            const float sc = A[t] / sm;
#pragma unroll
            for (int oo = 0; oo < 32; ++oo)
                Rm[oo * RS + t] = v[oo] * sc;
        }
        __syncthreads();

        // ===== pass 1 with r = R*a (pre-multiplied) =====
        PASS1(Rm[o * RS + n]);
        STATS((float)(it + 2));
    }

    // ===== write outputs: poses [pix][o][16] then a_out [pix][o] =====
    if (s == 0) {
        float4* ob = (float4*)(out + (size_t)pix * 512 + o * 16);
        ob[0] = m0; ob[1] = m1; ob[2] = m2; ob[3] = m3;
        out[401408 + pix * 32 + o] = a_out;
    }
}

extern "C" void kernel_launch(void* const* d_in, const int* in_sizes, int n_in,
                              void* d_out, int out_size, void* d_ws, size_t ws_size,
                              hipStream_t stream)
{
    const float* poses  = (const float*)d_in[0];
    const float* acts   = (const float*)d_in[1];
    const float* kern   = (const float*)d_in[2];
    const float* beta_a = (const float*)d_in[3];
    const float* beta_u = (const float*)d_in[4];
    float* out = (float*)d_out;
    convcaps_em<<<NBLK, 256, 0, stream>>>(poses, acts, kern, beta_a, beta_u, out);
}

// Round 6
// 102.481 us; speedup vs baseline: 10.0566x; 10.0566x over previous
//
#include <hip/hip_runtime.h>
#include <math.h>

#define NBLK 784
#define O_ 32
#define N_ 144
#define D_ 16
#define PS 20    // padded LDS row stride for P (floats); 80B rows, float4-aligned
#define RS 148   // padded LDS row stride for R (floats)

__global__ __launch_bounds__(256) void convcaps_em(
    const float* __restrict__ poses,
    const float* __restrict__ acts,
    const float* __restrict__ kern,
    const float* __restrict__ beta_a,
    const float* __restrict__ beta_u,
    float* __restrict__ out)
{
    const int pix = blockIdx.x;          // b*196 + ho*14 + wo
    const int b  = pix / 196;
    const int hw = pix - b * 196;
    const int ho = hw / 14;
    const int wo = hw - ho * 14;

    __shared__ __align__(16) float P[N_ * PS];   // pose blocks [n][d]
    __shared__ float A[N_];                      // a_in
    __shared__ float Rm[O_ * RS];                // R*a / logits [o][n]

    const int t = threadIdx.x;

    // ---- load pose block: P[n][d] = poses[b, ho+ki, wo+kj, c, d], n=(ki*3+kj)*16+c
    for (int idx = t; idx < N_ * D_; idx += 256) {
        int n = idx >> 4, d = idx & 15;
        int ki = n / 48, kj = (n >> 4) - ki * 3, c = n & 15;
        P[n * PS + d] = poses[((b * 16 + ho + ki) * 16 + (wo + kj)) * 256 + c * 16 + d];
    }
    if (t < N_) {
        int n = t;
        int ki = n / 48, kj = (n >> 4) - ki * 3, c = n & 15;
        A[n] = acts[((b * 16 + ho + ki) * 16 + (wo + kj)) * 16 + c];
    }
    __syncthreads();
    // ---- init R*a = A[n]/32  (R uniform 1/O; A premultiplied)
    for (int idx = t; idx < O_ * N_; idx += 256) {
        int oo = idx / N_;
        int nn = idx - oo * N_;
        Rm[oo * RS + nn] = 0.03125f * A[nn];
    }
    __syncthreads();

    const int o = t >> 3;                        // 32 capsules
    const int s = t & 7;                         // 8 lanes per capsule, n-slice
    const float buv = beta_u[o];
    const float ba  = beta_a[o];
    const float* Kbase = kern + (size_t)o * (N_ * D_);

    float a_out = 0.f;
    float mu[16];

    for (int it = 0; it < 3; ++it) {
        // ===== pass 1: S1 = Σ rV, S2 = Σ rV², rs = Σ r  (r = R*a from Rm) =====
        float S1[16], S2[16];
#pragma unroll
        for (int d = 0; d < 16; ++d) { S1[d] = 0.f; S2[d] = 0.f; }
        float rs = 0.f;

#pragma unroll 2
        for (int k = 0; k < 18; ++k) {
            const int n = s + (k << 3);
            const float r = Rm[o * RS + n];
            rs += r;
            float pv[16], kv[16];
            const float4* Pp = (const float4*)(P + n * PS);
            ((float4*)pv)[0] = Pp[0];
            ((float4*)pv)[1] = Pp[1];
            ((float4*)pv)[2] = Pp[2];
            ((float4*)pv)[3] = Pp[3];
            const float4* Kp = (const float4*)(Kbase + n * D_);
            ((float4*)kv)[0] = Kp[0];
            ((float4*)kv)[1] = Kp[1];
            ((float4*)kv)[2] = Kp[2];
            ((float4*)kv)[3] = Kp[3];
#pragma unroll
            for (int i = 0; i < 4; ++i) {
#pragma unroll
                for (int l = 0; l < 4; ++l) {
                    // V[i*4+l] = Σ_j P[n][i*4+j] * K[o,n][j*4+l]
                    float v = fmaf(pv[i*4+0], kv[0+l],
                              fmaf(pv[i*4+1], kv[4+l],
                              fmaf(pv[i*4+2], kv[8+l],
                                   pv[i*4+3] * kv[12+l])));
                    S1[i*4+l] = fmaf(r, v, S1[i*4+l]);
                    S2[i*4+l] = fmaf(r * v, v, S2[i*4+l]);
                }
            }
        }

        // allreduce over the 8 lanes sharing this o (butterfly, same wave)
#pragma unroll
        for (int m = 1; m < 8; m <<= 1) {
            rs += __shfl_xor(rs, m, 64);
#pragma unroll
            for (int d = 0; d < 16; ++d) {
                S1[d] += __shfl_xor(S1[d], m, 64);
                S2[d] += __shfl_xor(S2[d], m, 64);
            }
        }

        rs += 1e-9f;                              // r_sum = Σr + EPS
        const float inv_rs = 1.0f / rs;
        float sig[16];
#pragma unroll
        for (int d = 0; d < 16; ++d) {
            mu[d] = S1[d] * inv_rs;
            // sigma2 = E[V²] - mu² + EPS  (== Σ r (V-mu)² / rs + EPS)
            sig[d] = fmaf(-mu[d], mu[d], S2[d] * inv_rs) + 1e-9f;
        }
        // L = Σ_d log(sigma2_d), computed redundantly per-lane (static idx, no butterfly)
        const float L = __logf(sig[0]  * sig[1])  + __logf(sig[2]  * sig[3])
                      + __logf(sig[4]  * sig[5])  + __logf(sig[6]  * sig[7])
                      + __logf(sig[8]  * sig[9])  + __logf(sig[10] * sig[11])
                      + __logf(sig[12] * sig[13]) + __logf(sig[14] * sig[15]);
        // cost = rs*(D*beta_u + 0.5*L);  a_out = sigmoid(inv_temp*(ba - cost))
        const float cost = rs * fmaf(0.5f, L, 16.0f * buv);
        const float x = (float)(it + 1) * (ba - cost);
        a_out = 1.0f / (1.0f + __expf(-x));

        if (it < 2) {
            float isg[16];
#pragma unroll
            for (int d = 0; d < 16; ++d) isg[d] = 1.0f / sig[d];
            // logits = log(a_out+eps) - 0.5*(D*log(2pi) + L) - 0.5*Q
            const float LC = __logf(a_out + 1e-9f)
                           - 0.5f * (16.0f * 1.8378770664093453f + L);
            __syncthreads();   // all pass-1 Rm reads done before overwrite

            // ===== pass 2: logits into Rm =====
#pragma unroll 2
            for (int k = 0; k < 18; ++k) {
                const int n = s + (k << 3);
                float pv[16], kv[16];
                const float4* Pp = (const float4*)(P + n * PS);
                ((float4*)pv)[0] = Pp[0];
                ((float4*)pv)[1] = Pp[1];
                ((float4*)pv)[2] = Pp[2];
                ((float4*)pv)[3] = Pp[3];
                const float4* Kp = (const float4*)(Kbase + n * D_);
                ((float4*)kv)[0] = Kp[0];
                ((float4*)kv)[1] = Kp[1];
                ((float4*)kv)[2] = Kp[2];
                ((float4*)kv)[3] = Kp[3];
                float Q = 0.f;
#pragma unroll
                for (int i = 0; i < 4; ++i) {
#pragma unroll
                    for (int l = 0; l < 4; ++l) {
                        float v = fmaf(pv[i*4+0], kv[0+l],
                                  fmaf(pv[i*4+1], kv[4+l],
                                  fmaf(pv[i*4+2], kv[8+l],
                                       pv[i*4+3] * kv[12+l])));
                        const float df = v - mu[i*4+l];
                        Q = fmaf(df * df, isg[i*4+l], Q);
                    }
                }
                Rm[o * RS + n] = fmaf(-0.5f, Q, LC);
            }
            __syncthreads();

            // ===== softmax over o (one thread per n); store R*a pre-multiplied =====
            if (t < N_) {
                float v[32];
                float mx = -1e30f;
#pragma unroll
                for (int oo = 0; oo < 32; ++oo) {
                    v[oo] = Rm[oo * RS + t];
                    mx = fmaxf(mx, v[oo]);
                }
                float sm = 0.f;
#pragma unroll
                for (int oo = 0; oo < 32; ++oo) {
                    v[oo] = __expf(v[oo] - mx);
                    sm += v[oo];
                }
                const float sc = A[t] / sm;
#pragma unroll
                for (int oo = 0; oo < 32; ++oo)
                    Rm[oo * RS + t] = v[oo] * sc;
            }
            __syncthreads();
        }
    }

    // ===== write outputs: poses [pix][o][16] then a_out [pix][o] =====
    if (s == 0) {
        float4* ob = (float4*)(out + (size_t)pix * 512 + o * 16);
        ob[0] = make_float4(mu[0],  mu[1],  mu[2],  mu[3]);
        ob[1] = make_float4(mu[4],  mu[5],  mu[6],  mu[7]);
        ob[2] = make_float4(mu[8],  mu[9],  mu[10], mu[11]);
        ob[3] = make_float4(mu[12], mu[13], mu[14], mu[15]);
        out[401408 + pix * 32 + o] = a_out;
    }
}

extern "C" void kernel_launch(void* const* d_in, const int* in_sizes, int n_in,
                              void* d_out, int out_size, void* d_ws, size_t ws_size,
                              hipStream_t stream)
{
    const float* poses  = (const float*)d_in[0];
    const float* acts   = (const float*)d_in[1];
    const float* kern   = (const float*)d_in[2];
    const float* beta_a = (const float*)d_in[3];
    const float* beta_u = (const float*)d_in[4];
    float* out = (float*)d_out;
    convcaps_em<<<NBLK, 256, 0, stream>>>(poses, acts, kern, beta_a, beta_u, out);
}